// Round 1
// baseline (5449.776 us; speedup 1.0000x reference)
//
#include <hip/hip_runtime.h>

typedef _Float16 f16;
typedef _Float16 f16x8 __attribute__((ext_vector_type(8)));
typedef float    f32x4 __attribute__((ext_vector_type(4)));

#define NG 8       // batch groups (one per XCD), 8 m each
#define MB 8       // m per group
#define RS 32      // row-slice WGs per group
#define RI 64      // neuron rows per WG
#define NN 2048
#define TSTEPS 512
#define NWAVE 8
#define KPW 256    // K columns per wave
#define NCH 8      // 32-wide k-chunks per wave

__device__ __forceinline__ float fast_tanh(float x) {
    float e = __expf(2.0f * x);
    return 1.0f - 2.0f / (e + 1.0f);   // exact at +-inf saturation
}

// ws layout: u_buf f16 [2][NG][MB][NN] = 524288 B | flags int[256] (4 KB region) | y_ws f32 [64][2][512] = 256 KB
__global__ __launch_bounds__(512)
void rnn_persist(const float* __restrict__ Iin, const float* __restrict__ x0,
                 const float* __restrict__ W_in, const float* __restrict__ W_rec,
                 const float* __restrict__ b_rec, const float* __restrict__ W_out,
                 float* __restrict__ x_out, float* __restrict__ u_out,
                 f16* __restrict__ u_buf, int* __restrict__ flags,
                 float* __restrict__ y_ws)
{
    const int wg   = blockIdx.x;
    const int g    = wg & 7;        // group == XCD under bid%8 round-robin (perf only)
    const int r    = wg >> 3;       // row-slice within group
    const int tid  = threadIdx.x;
    const int lane = tid & 63;
    const int wv   = tid >> 6;      // 8 waves; wave wv owns K range [wv*256, wv*256+256)
    const int i_base = r * RI;
    const int m_base = g * MB;

    __shared__ float red[NWAVE][RI][9];       // K-split partials, +1 pad (18 KB)
    __shared__ float xstage[2][MB][RI][9];    // 8-step x staging, slot-dim padded (36 KB)
    __shared__ float x_s[MB][RI];             // persistent state (2 KB)

    const float x0v   = x0[0];
    const float alpha = (float)(0.02 / 0.1);

    // ---- load this wave's W_rec fragments into registers (held all 512 steps) ----
    const int arow = lane & 15;          // A-row (m) / B-col (i) lane mapping
    const int kseg = (lane >> 4) * 8;    // k sub-offset inside a 32-chunk
    f16x8 wf[4][NCH];                    // 4 i-tiles x 8 chunks = 128 VGPR
    #pragma unroll
    for (int it = 0; it < 4; ++it) {
        const int gi = i_base + it * 16 + arow;
        #pragma unroll
        for (int c = 0; c < NCH; ++c) {
            const int k = wv * KPW + c * 32 + kseg;
            const float4* p = (const float4*)(W_rec + (size_t)gi * NN + k);
            float4 w0 = p[0], w1 = p[1];
            f16x8 w;
            w[0]=(f16)w0.x; w[1]=(f16)w0.y; w[2]=(f16)w0.z; w[3]=(f16)w0.w;
            w[4]=(f16)w1.x; w[5]=(f16)w1.y; w[6]=(f16)w1.z; w[7]=(f16)w1.w;
            wf[it][c] = w;
        }
    }

    // ---- per-thread epilogue constants: element (m = wave, i = lane) ----
    const int em = wv, ei = lane;
    const int egm = m_base + em, egi = i_base + ei;
    const float wi0 = W_in[egi * 2 + 0], wi1 = W_in[egi * 2 + 1];
    const float brv = b_rec[egi];
    const float wo0 = W_out[0 * NN + egi], wo1 = W_out[1 * NN + egi];

    // ---- init: x_0 = x0 everywhere; publish u_0 ----
    const float u0 = fast_tanh(x0v);
    x_s[em][ei] = x0v;
    xstage[0][em][ei][0] = x0v;                                  // output slot p=0
    u_buf[(((size_t)0 * NG + g) * MB + em) * NN + egi] = (f16)u0;
    __syncthreads();   // drains vmcnt before barrier -> u_0 stores issued
    if (tid == 0)
        __hip_atomic_store(&flags[(g << 5) + r], 0, __ATOMIC_RELEASE, __HIP_MEMORY_SCOPE_AGENT);

    for (int t = 0; t < TSTEPS; ++t) {
        // 1. wait: all 32 producers of this group published u_t
        if (wv == 0) {
            if (lane < RS) {
                int guard = 0;
                while (__hip_atomic_load(&flags[(g << 5) + lane], __ATOMIC_RELAXED,
                                         __HIP_MEMORY_SCOPE_AGENT) < t) {
                    if (++guard > (1 << 28)) break;   // hang insurance -> wrong answer beats timeout
                }
            }
            __builtin_amdgcn_fence(__ATOMIC_ACQUIRE, "agent");    // invalidate stale L1/L2
        }
        __syncthreads();

        // 2. MFMA: D[16m x 64i] += u_t[16m x K] * W^T, this wave's K quarter
        const f16* ub = u_buf + (((size_t)(t & 1) * NG + g) * MB) * NN;
        f32x4 a0 = {0,0,0,0}, a1 = {0,0,0,0}, a2 = {0,0,0,0}, a3 = {0,0,0,0};
        #pragma unroll
        for (int c = 0; c < NCH; ++c) {
            const int k = wv * KPW + c * 32 + kseg;
            f16x8 av;
            #pragma unroll
            for (int z = 0; z < 8; ++z) av[z] = (f16)0;   // m rows 8..15 are padding
            if (arow < MB) av = *(const f16x8*)(ub + (size_t)arow * NN + k);
            a0 = __builtin_amdgcn_mfma_f32_16x16x32_f16(av, wf[0][c], a0, 0, 0, 0);
            a1 = __builtin_amdgcn_mfma_f32_16x16x32_f16(av, wf[1][c], a1, 0, 0, 0);
            a2 = __builtin_amdgcn_mfma_f32_16x16x32_f16(av, wf[2][c], a2, 0, 0, 0);
            a3 = __builtin_amdgcn_mfma_f32_16x16x32_f16(av, wf[3][c], a3, 0, 0, 0);
        }
        // 3. K-split partials -> LDS.  D layout: col=lane&15 (i), row=(lane>>4)*4+j (m); keep m<8
        if (lane < 32) {
            const int pm = (lane >> 4) * 4;
            #pragma unroll
            for (int j = 0; j < 4; ++j) {
                red[wv][ 0 + arow][pm + j] = a0[j];
                red[wv][16 + arow][pm + j] = a1[j];
                red[wv][32 + arow][pm + j] = a2[j];
                red[wv][48 + arow][pm + j] = a3[j];
            }
        }
        __syncthreads();

        // 4. epilogue: each thread owns one (m,i) element
        const int p = t + 1;
        float dot = 0.f;
        #pragma unroll
        for (int q = 0; q < NWAVE; ++q) dot += red[q][ei][em];
        const float I0  = Iin[((size_t)egm * 2 + 0) * TSTEPS + t];
        const float I1  = Iin[((size_t)egm * 2 + 1) * TSTEPS + t];
        const float cin = fmaf(wi0, I0, fmaf(wi1, I1, brv));
        const float xo  = x_s[em][ei];
        const float xn  = fmaf(alpha, dot + cin - xo, xo);   // x + a*(-x + Wu + WI + b)
        x_s[em][ei] = xn;
        const float un = fast_tanh(xn);
        xstage[(p >> 3) & 1][em][ei][p & 7] = xn;
        u_buf[(((size_t)(p & 1) * NG + g) * MB + em) * NN + egi] = (f16)un;

        // y[t] partial: wave == one m row, full-wave reduce over i
        float py0 = un * wo0, py1 = un * wo1;
        #pragma unroll
        for (int off = 32; off > 0; off >>= 1) {
            py0 += __shfl_xor(py0, off, 64);
            py1 += __shfl_xor(py1, off, 64);
        }
        if (lane == 0) {
            atomicAdd(&y_ws[((size_t)egm * 2 + 0) * TSTEPS + t], py0);
            atomicAdd(&y_ws[((size_t)egm * 2 + 1) * TSTEPS + t], py1);
        }

        // 5. flush staged outputs every 8 steps (t-contiguous 32B per thread)
        if ((p & 7) == 7 || p == TSTEPS) {
            const int nt = (p & 7) + 1;
            const int t0 = p + 1 - nt;
            const int bsel = (p >> 3) & 1;
            float* xp = x_out + ((size_t)egm * NN + egi) * (TSTEPS + 1) + t0;
            float* up = u_out + ((size_t)egm * NN + egi) * (TSTEPS + 1) + t0;
            for (int s = 0; s < nt; ++s) {
                const float v = xstage[bsel][em][ei][s];
                xp[s] = v;
                up[s] = fast_tanh(v);
            }
        }

        // 6. publish u_{t+1}: barrier drains all waves' vmcnt, then release flag
        __syncthreads();
        if (tid == 0)
            __hip_atomic_store(&flags[(g << 5) + r], p, __ATOMIC_RELEASE, __HIP_MEMORY_SCOPE_AGENT);
    }
}

__global__ void y_final(const float* __restrict__ y_ws, const float* __restrict__ b_out,
                        float* __restrict__ y_out)
{
    const int idx = blockIdx.x * 256 + threadIdx.x;     // 64*2*512 = 65536
    const int o = (idx >> 9) & 1;
    y_out[idx] = y_ws[idx] + b_out[o];
}

extern "C" void kernel_launch(void* const* d_in, const int* in_sizes, int n_in,
                              void* d_out, int out_size, void* d_ws, size_t ws_size,
                              hipStream_t stream) {
    const float* Iin   = (const float*)d_in[0];
    const float* x0    = (const float*)d_in[1];
    const float* W_in  = (const float*)d_in[2];
    const float* W_rec = (const float*)d_in[3];
    const float* b_rec = (const float*)d_in[4];
    const float* W_out = (const float*)d_in[5];
    const float* b_out = (const float*)d_in[6];

    float* out = (float*)d_out;
    const size_t XSZ = (size_t)64 * 2048 * 513;
    float* x_out = out;
    float* u_out = out + XSZ;
    float* y_out = out + 2 * XSZ;

    char* ws    = (char*)d_ws;
    f16*  u_buf = (f16*)ws;                               // 524288 B
    int*  flags = (int*)(ws + 524288);                    // 4096 B region
    float* y_ws = (float*)(ws + 524288 + 4096);           // 262144 B

    hipMemsetAsync(flags, 0xFF, 4096, stream);            // flags = -1 (unpublished)
    hipMemsetAsync(y_ws, 0, 262144, stream);
    rnn_persist<<<dim3(256), dim3(512), 0, stream>>>(Iin, x0, W_in, W_rec, b_rec, W_out,
                                                     x_out, u_out, u_buf, flags, y_ws);
    y_final<<<dim3(256), dim3(256), 0, stream>>>(y_ws, b_out, y_out);
}